// Round 11
// baseline (954.269 us; speedup 1.0000x reference)
//
#include <hip/hip_runtime.h>
#include <hip/hip_cooperative_groups.h>
#include <math.h>

namespace cg = cooperative_groups;

typedef unsigned int u32;
typedef unsigned long long u64;
typedef float f32x4 __attribute__((ext_vector_type(4)));

#define NBKT 65536   // 16-bit prefix buckets
#define RANK_CAP 32768
#define MB 1024      // mega grid blocks (4/CU on 256 CUs -- safe co-residency)
#define MT 256

// ===== Bit-exact replica of XLA's f32 tanh =====
__device__ __forceinline__ float xla_tanhf(float x) {
    float xc = fminf(fmaxf(x, -9.0f), 9.0f);
    float x2 = __fmul_rn(xc, xc);
    float p = -2.76076847742355e-16f;
    p = __fadd_rn(__fmul_rn(p, x2),  2.00018790482477e-13f);
    p = __fadd_rn(__fmul_rn(p, x2), -8.60467152213735e-11f);
    p = __fadd_rn(__fmul_rn(p, x2),  5.12229709037114e-08f);
    p = __fadd_rn(__fmul_rn(p, x2),  1.48572235717979e-05f);
    p = __fadd_rn(__fmul_rn(p, x2),  6.37261928875436e-04f);
    p = __fadd_rn(__fmul_rn(p, x2),  4.89352455891786e-03f);
    p = __fmul_rn(xc, p);
    float q = 1.19825839466702e-06f;
    q = __fadd_rn(__fmul_rn(q, x2),  1.18534705686654e-04f);
    q = __fadd_rn(__fmul_rn(q, x2),  2.26843463243900e-03f);
    q = __fadd_rn(__fmul_rn(q, x2),  4.89352518554385e-03f);
    float r = p / q;
    return (fabsf(x) < 0.0004f) ? x : r;
}

__device__ __forceinline__ u32 key_desc(float f) {
    u32 u = __float_as_uint(f);
    u = (u & 0x80000000u) ? ~u : (u | 0x80000000u);
    return ~u;
}

struct Params {
    const float* x; const float* score; const int* ei; const float* eattr;
    const int* ntype; const float* elen;
    float* out;
    int N, D, E, DE, k;
    float* s; u32* hist; u32* cursor; u32* flags; u32* scan;
    u32* part; u32* partScan; u64* pack; u32* pay; int* cluster;
    long long o_xp, o_ei, o_eattr, o_nt, o_perm, o_vals, o_elen, o_emask;
};

__global__ __launch_bounds__(MT, 4) void mega(Params P) {
    cg::grid_group grid = cg::this_grid();
    __shared__ u32 sh[256];
    const int tid = blockIdx.x * MT + threadIdx.x;
    const int nth = gridDim.x * MT;
    const int t = threadIdx.x;

    // P0: zero hist+cursor+flags (contiguous in ws)
    for (int i = tid; i < 2 * NBKT + 2; i += nth) P.hist[i] = 0u;
    grid.sync();

    // P1: tanh table + cluster init + bucket histogram + int-width detect
    for (int i = tid; i < P.N; i += nth) {
        float tv = xla_tanhf(P.score[i]);
        P.s[i] = tv;
        P.cluster[i] = -1;
        atomicAdd(&P.hist[key_desc(tv) >> 16], 1u);
    }
    if (tid < 2048) { if (P.ei[2 * tid + 1] != 0) atomicOr(&P.flags[0], 1u); }
    else if (tid < 4096) { int i = tid - 2048; if (P.ntype[2 * i + 1] != 0) atomicOr(&P.flags[1], 1u); }
    grid.sync();

    // P2: per-256-chunk reduce (blocks 0..255)
    if (blockIdx.x < 256) {
        int b = blockIdx.x;
        sh[t] = P.hist[b * 256 + t];
        __syncthreads();
        for (int off = 128; off > 0; off >>= 1) { if (t < off) sh[t] += sh[t + off]; __syncthreads(); }
        if (t == 0) P.part[b] = sh[0];
    }
    grid.sync();

    // P3: exclusive scan of 256 partials (block 0)
    if (blockIdx.x == 0) {
        u32 v = P.part[t];
        sh[t] = v; __syncthreads();
        for (int off = 1; off < 256; off <<= 1) {
            u32 a = sh[t]; u32 b2 = (t >= off) ? sh[t - off] : 0u; __syncthreads();
            sh[t] = a + b2; __syncthreads();
        }
        P.partScan[t] = sh[t] - v;
        if (t == 255) P.scan[NBKT] = sh[255];
    }
    grid.sync();

    // P4: chunk-local exclusive scan + base (blocks 0..255)
    if (blockIdx.x < 256) {
        int b = blockIdx.x;
        u32 v = P.hist[b * 256 + t];
        sh[t] = v; __syncthreads();
        for (int off = 1; off < 256; off <<= 1) {
            u32 a = sh[t]; u32 b2 = (t >= off) ? sh[t - off] : 0u; __syncthreads();
            sh[t] = a + b2; __syncthreads();
        }
        P.scan[b * 256 + t] = P.partScan[b] + sh[t] - v;
    }
    grid.sync();

    // P5: scatter packed (key<<32|idx) into bucket ranges
    for (int i = tid; i < P.N; i += nth) {
        u32 kk = key_desc(P.s[i]);
        u32 b = kk >> 16;
        u32 pos = P.scan[b] + atomicAdd(&P.cursor[b], 1u);
        if (pos < (u32)P.N) P.pack[pos] = ((u64)kk << 32) | (u32)i;
    }
    grid.sync();

    // P6: exact in-bucket rank (single u64 compare) + perm outputs
    for (int i = tid; i < P.N; i += nth) {
        u64 pk = P.pack[i];
        u32 b = (u32)(pk >> 48);
        u32 lo = P.scan[b], hi = P.scan[b + 1];
        if (hi > (u32)P.N) hi = (u32)P.N;
        if (hi > lo + RANK_CAP) hi = lo + RANK_CAP;
        u32 r = lo;
        for (u32 q = lo; q < hi; ++q) r += (P.pack[q] < pk);
        if (r < (u32)P.k) {
            u32 ip = (u32)pk;
            if (ip >= (u32)P.N) ip = 0;     // defensive
            P.pay[r] = ip;
            P.cluster[ip] = (int)r;
            P.out[P.o_perm + r] = (float)ip;
            P.out[P.o_vals + r] = P.s[ip];
            int nt = (P.flags[1] == 0u) ? P.ntype[2 * (size_t)ip] : P.ntype[ip];
            P.out[P.o_nt + r] = (float)nt;
        }
    }
    grid.sync();

    // P7: x-gather (gx) + quad-fused edges/attr (ea), one combined index space
    const int Dv = P.D / 4;
    const long long gxTot = (long long)P.k * Dv;      // multiple of 4
    const long long eaTot = (long long)P.E * 4;
    const bool w64 = (P.flags[0] == 0u);
    const f32x4* x4 = (const f32x4*)P.x;
    f32x4* oxp4 = (f32x4*)(P.out + P.o_xp);
    const f32x4* attr4 = (const f32x4*)P.eattr;
    f32x4* oattr4 = (f32x4*)(P.out + P.o_eattr);
    float* o_ei0 = P.out + P.o_ei;
    float* o_len = P.out + P.o_elen;
    float* o_msk = P.out + P.o_emask;
    for (long long idx = tid; idx < gxTot + eaTot; idx += nth) {
        if (idx < gxTot) {
            int r = (int)(idx / Dv);
            int c = (int)(idx - (long long)r * Dv);
            u32 p = P.pay[r];
            if (p >= (u32)P.N) p = 0;       // defensive
            float v = P.s[p];
            f32x4 a = x4[(size_t)p * Dv + c];
            a = a * v;
            __builtin_nontemporal_store(a, oxp4 + idx);
        } else {
            long long eidx = idx - gxTot;   // quad-aligned: (eidx&3) == (lane&3)
            int e = (int)(eidx >> 2);
            int mfl = 0;
            if ((eidx & 3) == 0) {
                int a, b;
                if (w64) {
                    a = ((const int2*)P.ei)[e].x;
                    b = ((const int2*)P.ei)[(size_t)P.E + e].x;
                } else {
                    a = P.ei[e]; b = P.ei[P.E + e];
                }
                bool ok = ((u32)a < (u32)P.N) && ((u32)b < (u32)P.N);
                int r  = ok ? P.cluster[a] : -1;
                int cc = ok ? P.cluster[b] : -1;
                bool m = (r >= 0) && (cc >= 0);
                mfl = m ? 1 : 0;
                __builtin_nontemporal_store(m ? (float)r  : 0.0f, o_ei0 + e);
                __builtin_nontemporal_store(m ? (float)cc : 0.0f, o_ei0 + (size_t)P.E + e);
                __builtin_nontemporal_store(m ? P.elen[e] : 0.0f, o_len + e);
                __builtin_nontemporal_store(m ? 1.0f : 0.0f, o_msk + e);
            }
            int lane = threadIdx.x & 63;
            mfl = __shfl(mfl, lane & ~3);   // quad leader -> quad (same branch)
            f32x4 v = {0.f, 0.f, 0.f, 0.f};
            if (mfl) v = attr4[eidx];
            __builtin_nontemporal_store(v, oattr4 + eidx);
        }
    }
}

// ================= fallback multi-kernel chain (R10, proven) =================
__global__ void k_zero(u32* __restrict__ p, int n) {
    int i = blockIdx.x * blockDim.x + threadIdx.x;
    if (i < n) p[i] = 0;
}
__global__ void k_detect2(const int* __restrict__ ei, const int* __restrict__ nt,
                          u32* __restrict__ flags) {
    int b = blockIdx.x, t = threadIdx.x;
    if (b < 8) { int i = b * 256 + t; if (ei[2 * i + 1] != 0) atomicOr(&flags[0], 1u); }
    else { int i = (b - 8) * 256 + t; if (nt[2 * i + 1] != 0) atomicOr(&flags[1], 1u); }
}
__global__ void k_prep(const float* __restrict__ score, float* __restrict__ s,
                       int* __restrict__ cluster, u32* __restrict__ hist, int N) {
    int i = blockIdx.x * blockDim.x + threadIdx.x;
    if (i < N) {
        float t = xla_tanhf(score[i]);
        s[i] = t; cluster[i] = -1;
        atomicAdd(&hist[key_desc(t) >> 16], 1u);
    }
}
__global__ void k_scan1(const u32* __restrict__ hist, u32* __restrict__ part) {
    __shared__ u32 sh[256];
    int b = blockIdx.x, t = threadIdx.x;
    sh[t] = hist[b * 256 + t]; __syncthreads();
    for (int off = 128; off > 0; off >>= 1) { if (t < off) sh[t] += sh[t + off]; __syncthreads(); }
    if (t == 0) part[b] = sh[0];
}
__global__ void k_scan2(const u32* __restrict__ part, u32* __restrict__ partScan,
                        u32* __restrict__ scan) {
    __shared__ u32 sh[256];
    int t = threadIdx.x;
    u32 v = part[t]; sh[t] = v; __syncthreads();
    for (int off = 1; off < 256; off <<= 1) {
        u32 x = sh[t]; u32 y = (t >= off) ? sh[t - off] : 0u; __syncthreads();
        sh[t] = x + y; __syncthreads();
    }
    partScan[t] = sh[t] - v;
    if (t == 255) scan[NBKT] = sh[255];
}
__global__ void k_scan3(const u32* __restrict__ hist, const u32* __restrict__ partScan,
                        u32* __restrict__ scan) {
    __shared__ u32 sh[256];
    int b = blockIdx.x, t = threadIdx.x;
    u32 v = hist[b * 256 + t]; sh[t] = v; __syncthreads();
    for (int off = 1; off < 256; off <<= 1) {
        u32 x = sh[t]; u32 y = (t >= off) ? sh[t - off] : 0u; __syncthreads();
        sh[t] = x + y; __syncthreads();
    }
    scan[b * 256 + t] = partScan[b] + sh[t] - v;
}
__global__ void k_scat(const float* __restrict__ s, const u32* __restrict__ scan,
                       u32* __restrict__ cursor, u64* __restrict__ pack, int N) {
    int i = blockIdx.x * blockDim.x + threadIdx.x;
    if (i < N) {
        u32 kk = key_desc(s[i]);
        u32 b = kk >> 16;
        u32 pos = scan[b] + atomicAdd(&cursor[b], 1u);
        if (pos < (u32)N) pack[pos] = ((u64)kk << 32) | (u32)i;
    }
}
__global__ void k_rankperm(const u32* __restrict__ scan, const u64* __restrict__ pack,
                           u32* __restrict__ pay, const float* __restrict__ s,
                           const int* __restrict__ ntype, const u32* __restrict__ ntFlag,
                           int* __restrict__ cluster,
                           float* __restrict__ o_nt, float* __restrict__ o_perm,
                           float* __restrict__ o_vals, int k, int N) {
    int i = blockIdx.x * blockDim.x + threadIdx.x;
    if (i < N) {
        u64 pk = pack[i];
        u32 b = (u32)(pk >> 48);
        u32 lo = scan[b], hi = scan[b + 1];
        if (hi > (u32)N) hi = (u32)N;
        if (hi > lo + RANK_CAP) hi = lo + RANK_CAP;
        u32 r = lo;
        for (u32 q = lo; q < hi; ++q) r += (pack[q] < pk);
        if (r < (u32)k) {
            u32 ip = (u32)pk;
            if (ip >= (u32)N) ip = 0;
            pay[r] = ip; cluster[ip] = (int)r;
            o_perm[r] = (float)ip; o_vals[r] = s[ip];
            int nt = (*ntFlag == 0u) ? ntype[2 * (size_t)ip] : ntype[ip];
            o_nt[r] = (float)nt;
        }
    }
}
__global__ void k_gx(const u32* __restrict__ pay, const float* __restrict__ s,
                     const f32x4* __restrict__ x4, f32x4* __restrict__ out4,
                     int k, int Dv, int N) {
    int idx = blockIdx.x * blockDim.x + threadIdx.x;
    if (idx < k * Dv) {
        int r = idx / Dv, c = idx - r * Dv;
        u32 p = pay[r];
        if (p >= (u32)N) p = 0;
        float v = s[p];
        f32x4 a = x4[(size_t)p * Dv + c];
        a = a * v;
        __builtin_nontemporal_store(a, out4 + idx);
    }
}
__global__ void k_ea(const int* __restrict__ ei, const u32* __restrict__ eiFlag,
                     const float* __restrict__ elen, const int* __restrict__ cluster,
                     const f32x4* __restrict__ attr4,
                     float* __restrict__ o_ei, float* __restrict__ o_len,
                     float* __restrict__ o_mask, f32x4* __restrict__ o_attr4,
                     int E, int N) {
    const int total = E * 4;
    const int stride = gridDim.x * blockDim.x;
    const bool w64 = (*eiFlag == 0u);
    for (int idx = blockIdx.x * blockDim.x + threadIdx.x; idx < total; idx += stride) {
        int e = idx >> 2, c = idx & 3;
        int mfl = 0;
        if (c == 0) {
            int a, b;
            if (w64) { a = ((const int2*)ei)[e].x; b = ((const int2*)ei)[(size_t)E + e].x; }
            else { a = ei[e]; b = ei[E + e]; }
            bool ok = ((u32)a < (u32)N) && ((u32)b < (u32)N);
            int r = ok ? cluster[a] : -1;
            int cc = ok ? cluster[b] : -1;
            bool m = (r >= 0) && (cc >= 0);
            mfl = m ? 1 : 0;
            __builtin_nontemporal_store(m ? (float)r  : 0.0f, o_ei + e);
            __builtin_nontemporal_store(m ? (float)cc : 0.0f, o_ei + (size_t)E + e);
            __builtin_nontemporal_store(m ? elen[e] : 0.0f, o_len + e);
            __builtin_nontemporal_store(m ? 1.0f : 0.0f, o_mask + e);
        }
        int lane = threadIdx.x & 63;
        mfl = __shfl(mfl, lane & ~3);
        f32x4 v = {0.f, 0.f, 0.f, 0.f};
        if (mfl) v = attr4[idx];
        __builtin_nontemporal_store(v, o_attr4 + idx);
    }
}

extern "C" void kernel_launch(void* const* d_in, const int* in_sizes, int n_in,
                              void* d_out, int out_size, void* d_ws, size_t ws_size,
                              hipStream_t stream) {
    const float* x     = (const float*)d_in[0];
    const float* score = (const float*)d_in[1];
    const int*   ei    = (const int*)d_in[2];
    const float* eattr = (const float*)d_in[3];
    const int*   ntype = (const int*)d_in[4];
    const float* elen  = (const float*)d_in[5];

    const int N  = in_sizes[1];
    const int D  = in_sizes[0] / N;
    const int E  = in_sizes[5];
    const int DE = in_sizes[3] / E;
    const int k  = (N + 1) / 2;     // ceil(0.5 * N)

    float* out = (float*)d_out;
    const long long o_xp    = 0;
    const long long o_ei    = o_xp    + (long long)k * D;
    const long long o_eattr = o_ei    + 2 * (long long)E;
    const long long o_nt    = o_eattr + (long long)E * DE;
    const long long o_perm  = o_nt    + k;
    const long long o_vals  = o_perm  + k;
    const long long o_elen  = o_vals  + k;
    const long long o_emask = o_elen  + E;

    char* ws = (char*)d_ws;
    u64* pack    = (u64*)ws;     ws += 8 * (size_t)N;       // 8B-aligned first
    float* s     = (float*)ws;   ws += 4 * (size_t)N;
    u32* hist    = (u32*)ws;     ws += 4 * (size_t)NBKT;
    u32* cursor  = (u32*)ws;     ws += 4 * (size_t)NBKT;    // contiguous with hist
    u32* flags   = (u32*)ws;     ws += 4 * 2;               // contiguous: zeroed together
    u32* scan    = (u32*)ws;     ws += 4 * ((size_t)NBKT + 2);
    u32* part    = (u32*)ws;     ws += 4 * 256;
    u32* partScan= (u32*)ws;     ws += 4 * 256;
    u32* pay     = (u32*)ws;     ws += 4 * (size_t)N;
    int* cluster = (int*)ws;     ws += 4 * (size_t)N;

    Params P;
    P.x = x; P.score = score; P.ei = ei; P.eattr = eattr; P.ntype = ntype; P.elen = elen;
    P.out = out; P.N = N; P.D = D; P.E = E; P.DE = DE; P.k = k;
    P.s = s; P.hist = hist; P.cursor = cursor; P.flags = flags; P.scan = scan;
    P.part = part; P.partScan = partScan; P.pack = pack; P.pay = pay; P.cluster = cluster;
    P.o_xp = o_xp; P.o_ei = o_ei; P.o_eattr = o_eattr; P.o_nt = o_nt;
    P.o_perm = o_perm; P.o_vals = o_vals; P.o_elen = o_elen; P.o_emask = o_emask;

    void* args[] = { (void*)&P };
    hipError_t err = hipLaunchCooperativeKernel(mega, dim3(MB), dim3(MT), args, 0u, stream);
    if (err != hipSuccess) {
        // fallback: proven multi-kernel chain (identical semantics)
        const int nbN = (N + 255) / 256;
        k_zero<<<(2 * NBKT + 2 + 255) / 256, 256, 0, stream>>>(hist, 2 * NBKT + 2);
        k_detect2<<<16, 256, 0, stream>>>(ei, ntype, flags);
        k_prep<<<nbN, 256, 0, stream>>>(score, s, cluster, hist, N);
        k_scan1<<<256, 256, 0, stream>>>(hist, part);
        k_scan2<<<1, 256, 0, stream>>>(part, partScan, scan);
        k_scan3<<<256, 256, 0, stream>>>(hist, partScan, scan);
        k_scat<<<nbN, 256, 0, stream>>>(s, scan, cursor, pack, N);
        k_rankperm<<<nbN, 256, 0, stream>>>(scan, pack, pay, s, ntype, &flags[1], cluster,
                                            out + o_nt, out + o_perm, out + o_vals, k, N);
        const int Dv = D / 4;
        const int gx = k * Dv;
        k_gx<<<(gx + 255) / 256, 256, 0, stream>>>(pay, s, (const f32x4*)x,
                                                   (f32x4*)(out + o_xp), k, Dv, N);
        k_ea<<<2048, 256, 0, stream>>>(ei, &flags[0], elen, cluster,
                                       (const f32x4*)eattr,
                                       out + o_ei, out + o_elen, out + o_emask,
                                       (f32x4*)(out + o_eattr), E, N);
    }
}

// Round 13
// 279.973 us; speedup vs baseline: 3.4084x; 3.4084x over previous
//
#include <hip/hip_runtime.h>
#include <math.h>

typedef unsigned int u32;
typedef unsigned long long u64;
typedef float f32x4 __attribute__((ext_vector_type(4)));

#define NBKT 65536   // 16-bit prefix buckets
#define RANK_CAP 32768

// ===== Bit-exact replica of XLA's f32 tanh =====
__device__ __forceinline__ float xla_tanhf(float x) {
    float xc = fminf(fmaxf(x, -9.0f), 9.0f);
    float x2 = __fmul_rn(xc, xc);
    float p = -2.76076847742355e-16f;
    p = __fadd_rn(__fmul_rn(p, x2),  2.00018790482477e-13f);
    p = __fadd_rn(__fmul_rn(p, x2), -8.60467152213735e-11f);
    p = __fadd_rn(__fmul_rn(p, x2),  5.12229709037114e-08f);
    p = __fadd_rn(__fmul_rn(p, x2),  1.48572235717979e-05f);
    p = __fadd_rn(__fmul_rn(p, x2),  6.37261928875436e-04f);
    p = __fadd_rn(__fmul_rn(p, x2),  4.89352455891786e-03f);
    p = __fmul_rn(xc, p);
    float q = 1.19825839466702e-06f;
    q = __fadd_rn(__fmul_rn(q, x2),  1.18534705686654e-04f);
    q = __fadd_rn(__fmul_rn(q, x2),  2.26843463243900e-03f);
    q = __fadd_rn(__fmul_rn(q, x2),  4.89352518554385e-03f);
    float r = p / q;                     // IEEE f32 divide
    return (fabsf(x) < 0.0004f) ? x : r;
}

__device__ __forceinline__ u32 key_desc(float f) {
    u32 u = __float_as_uint(f);
    u = (u & 0x80000000u) ? ~u : (u | 0x80000000u);
    return ~u;
}

// zero hist + flags (contiguous)
__global__ void k_zero(u32* __restrict__ p, int n) {
    int i = blockIdx.x * blockDim.x + threadIdx.x;
    if (i < n) p[i] = 0;
}

// tanh table + cluster init + bucket histogram + int64/int32 layout detect
__global__ void k_prep(const float* __restrict__ score, float* __restrict__ s,
                       int* __restrict__ cluster, u32* __restrict__ hist,
                       const int* __restrict__ ei, const int* __restrict__ ntype,
                       u32* __restrict__ flags, int N) {
    int i = blockIdx.x * blockDim.x + threadIdx.x;
    if (i < 2048) { if (ei[2 * i + 1] != 0) atomicOr(&flags[0], 1u); }
    else if (i < 4096) { int j = i - 2048; if (ntype[2 * j + 1] != 0) atomicOr(&flags[1], 1u); }
    if (i < N) {
        float t = xla_tanhf(score[i]);
        s[i] = t;
        cluster[i] = -1;
        atomicAdd(&hist[key_desc(t) >> 16], 1u);
    }
}

// 256 blocks: block b reduces hist[b*256 .. +255] -> part[b]
__global__ void k_scanA(const u32* __restrict__ hist, u32* __restrict__ part) {
    __shared__ u32 sh[256];
    int b = blockIdx.x, t = threadIdx.x;
    sh[t] = hist[b * 256 + t];
    __syncthreads();
    for (int off = 128; off > 0; off >>= 1) {
        if (t < off) sh[t] += sh[t + off];
        __syncthreads();
    }
    if (t == 0) part[b] = sh[0];
}

// 256 blocks: block b computes base = sum(part[0..b)), chunk-scans, and writes
// BOTH scan[] and cursor[] (cursor pre-based => no separate cursor init)
__global__ void k_scanB(const u32* __restrict__ hist, const u32* __restrict__ part,
                        u32* __restrict__ scan, u32* __restrict__ cursor) {
    __shared__ u32 sh[256];
    __shared__ u32 base_sh;
    int b = blockIdx.x, t = threadIdx.x;
    u32 acc = (t < b) ? part[t] : 0u;
    sh[t] = acc;
    __syncthreads();
    for (int off = 128; off > 0; off >>= 1) {
        if (t < off) sh[t] += sh[t + off];
        __syncthreads();
    }
    if (t == 0) base_sh = sh[0];
    __syncthreads();
    u32 base = base_sh;
    u32 v = hist[b * 256 + t];
    sh[t] = v;
    __syncthreads();
    for (int off = 1; off < 256; off <<= 1) {
        u32 x = sh[t];
        u32 y = (t >= off) ? sh[t - off] : 0u;
        __syncthreads();
        sh[t] = x + y;
        __syncthreads();
    }
    u32 ex = base + sh[t] - v;           // exclusive prefix
    scan[b * 256 + t] = ex;
    cursor[b * 256 + t] = ex;
    if (b == 255 && t == 255) scan[NBKT] = ex + v;   // total = N
}

// scatter packed (key<<32|idx); cursor already holds the bucket base
__global__ void k_scat(const float* __restrict__ s, u32* __restrict__ cursor,
                       u64* __restrict__ pack, int N) {
    int i = blockIdx.x * blockDim.x + threadIdx.x;
    if (i < N) {
        u32 kk = key_desc(s[i]);
        u32 pos = atomicAdd(&cursor[kk >> 16], 1u);
        if (pos < (u32)N) pack[pos] = ((u64)kk << 32) | (u32)i;
    }
}

// exact in-bucket rank (single u64 compare) + fused perm outputs
__global__ void k_rankperm(const u32* __restrict__ scan, const u64* __restrict__ pack,
                           u32* __restrict__ pay, const float* __restrict__ s,
                           const int* __restrict__ ntype, const u32* __restrict__ ntFlag,
                           int* __restrict__ cluster,
                           float* __restrict__ o_nt, float* __restrict__ o_perm,
                           float* __restrict__ o_vals, int k, int N) {
    int i = blockIdx.x * blockDim.x + threadIdx.x;
    if (i < N) {
        u64 pk = pack[i];
        u32 b = (u32)(pk >> 48);
        u32 lo = scan[b], hi = scan[b + 1];
        if (hi > (u32)N) hi = (u32)N;
        if (hi > lo + RANK_CAP) hi = lo + RANK_CAP;
        u32 r = lo;
        for (u32 q = lo; q < hi; ++q) r += (pack[q] < pk);
        if (r < (u32)k) {
            u32 ip = (u32)pk;
            if (ip >= (u32)N) ip = 0;      // defensive
            pay[r] = ip;
            cluster[ip] = (int)r;
            o_perm[r] = (float)ip;
            o_vals[r] = s[ip];
            int nt = (*ntFlag == 0u) ? ntype[2 * (size_t)ip] : ntype[ip];
            o_nt[r] = (float)nt;
        }
    }
}

// combined x-gather + quad-fused edges/attr (structure proven in R11's mega P7)
__global__ void k_gxea(const u32* __restrict__ pay, const float* __restrict__ s,
                       const f32x4* __restrict__ x4, f32x4* __restrict__ oxp4,
                       const int* __restrict__ ei, const u32* __restrict__ eiFlag,
                       const float* __restrict__ elen, const int* __restrict__ cluster,
                       const f32x4* __restrict__ attr4,
                       float* __restrict__ o_ei, float* __restrict__ o_len,
                       float* __restrict__ o_mask, f32x4* __restrict__ o_attr4,
                       int k, int Dv, int E, int N) {
    const long long gxTot = (long long)k * Dv;        // multiple of 4
    const long long total = gxTot + (long long)E * 4;
    const long long nth = (long long)gridDim.x * blockDim.x;
    const bool w64 = (*eiFlag == 0u);
    for (long long idx = blockIdx.x * (long long)blockDim.x + threadIdx.x;
         idx < total; idx += nth) {
        if (idx < gxTot) {
            int r = (int)(idx / Dv);
            int c = (int)(idx - (long long)r * Dv);
            u32 p = pay[r];
            if (p >= (u32)N) p = 0;        // defensive
            float v = s[p];
            f32x4 a = x4[(size_t)p * Dv + c];
            a = a * v;
            __builtin_nontemporal_store(a, oxp4 + idx);
        } else {
            long long eidx = idx - gxTot;  // (eidx&3) == (lane&3) alignment holds
            int e = (int)(eidx >> 2);
            int mfl = 0;
            if ((eidx & 3) == 0) {
                int a, b;
                if (w64) {   // int64 LE: low word at 2*e (scalar NT loads)
                    a = __builtin_nontemporal_load(ei + 2 * (size_t)e);
                    b = __builtin_nontemporal_load(ei + 2 * ((size_t)E + (size_t)e));
                } else {
                    a = __builtin_nontemporal_load(ei + e);
                    b = __builtin_nontemporal_load(ei + (size_t)E + e);
                }
                bool ok = ((u32)a < (u32)N) && ((u32)b < (u32)N);
                int r  = ok ? cluster[a] : -1;
                int cc = ok ? cluster[b] : -1;
                bool m = (r >= 0) && (cc >= 0);
                mfl = m ? 1 : 0;
                __builtin_nontemporal_store(m ? (float)r  : 0.0f, o_ei + e);
                __builtin_nontemporal_store(m ? (float)cc : 0.0f, o_ei + (size_t)E + e);
                float el = __builtin_nontemporal_load(elen + e);
                __builtin_nontemporal_store(m ? el : 0.0f, o_len + e);
                __builtin_nontemporal_store(m ? 1.0f : 0.0f, o_mask + e);
            }
            int lane = threadIdx.x & 63;
            mfl = __shfl(mfl, lane & ~3);
            f32x4 v = {0.f, 0.f, 0.f, 0.f};
            if (mfl) v = __builtin_nontemporal_load(attr4 + eidx);
            __builtin_nontemporal_store(v, o_attr4 + eidx);
        }
    }
}

extern "C" void kernel_launch(void* const* d_in, const int* in_sizes, int n_in,
                              void* d_out, int out_size, void* d_ws, size_t ws_size,
                              hipStream_t stream) {
    const float* x     = (const float*)d_in[0];
    const float* score = (const float*)d_in[1];
    const int*   ei    = (const int*)d_in[2];
    const float* eattr = (const float*)d_in[3];
    const int*   ntype = (const int*)d_in[4];
    const float* elen  = (const float*)d_in[5];

    const int N  = in_sizes[1];
    const int D  = in_sizes[0] / N;
    const int E  = in_sizes[5];
    const int DE = in_sizes[3] / E;
    const int k  = (N + 1) / 2;     // ceil(0.5 * N)

    // d_out is FLOAT32. RETURN-ORDER layout:
    // x_p | edge_index | edge_attr_p | node_type | perm | vals | edge_lengths | edge_mask
    float* out = (float*)d_out;
    const size_t o_xp    = 0;
    const size_t o_ei    = o_xp    + (size_t)k * D;
    const size_t o_eattr = o_ei    + 2 * (size_t)E;
    const size_t o_nt    = o_eattr + (size_t)E * DE;
    const size_t o_perm  = o_nt    + (size_t)k;
    const size_t o_vals  = o_perm  + (size_t)k;
    const size_t o_elen  = o_vals  + (size_t)k;
    const size_t o_emask = o_elen  + (size_t)E;

    char* ws = (char*)d_ws;
    u64* pack    = (u64*)ws;     ws += 8 * (size_t)N;       // 8B-aligned first
    float* s     = (float*)ws;   ws += 4 * (size_t)N;
    u32* hist    = (u32*)ws;     ws += 4 * (size_t)NBKT;
    u32* flags   = (u32*)ws;     ws += 4 * 2;               // contiguous with hist: zeroed together
    u32* scan    = (u32*)ws;     ws += 4 * ((size_t)NBKT + 2);
    u32* cursor  = (u32*)ws;     ws += 4 * (size_t)NBKT;    // init'd by k_scanB
    u32* part    = (u32*)ws;     ws += 4 * 256;
    u32* pay     = (u32*)ws;     ws += 4 * (size_t)N;
    int* cluster = (int*)ws;     ws += 4 * (size_t)N;

    const int nbN = (N + 255) / 256;
    k_zero<<<(NBKT + 2 + 255) / 256, 256, 0, stream>>>(hist, NBKT + 2);
    k_prep<<<nbN, 256, 0, stream>>>(score, s, cluster, hist, ei, ntype, flags, N);
    k_scanA<<<256, 256, 0, stream>>>(hist, part);
    k_scanB<<<256, 256, 0, stream>>>(hist, part, scan, cursor);
    k_scat<<<nbN, 256, 0, stream>>>(s, cursor, pack, N);
    k_rankperm<<<nbN, 256, 0, stream>>>(scan, pack, pay, s, ntype, &flags[1], cluster,
                                        out + o_nt, out + o_perm, out + o_vals, k, N);
    const int Dv = D / 4;
    k_gxea<<<2048, 256, 0, stream>>>(pay, s, (const f32x4*)x, (f32x4*)(out + o_xp),
                                     ei, &flags[0], elen, cluster,
                                     (const f32x4*)eattr,
                                     out + o_ei, out + o_elen, out + o_emask,
                                     (f32x4*)(out + o_eattr), k, Dv, E, N);
}

// Round 14
// 200.129 us; speedup vs baseline: 4.7683x; 1.3990x over previous
//
#include <hip/hip_runtime.h>
#include <math.h>

typedef unsigned int u32;
typedef unsigned long long u64;
typedef float f32x4 __attribute__((ext_vector_type(4)));

#define NBKT 65536   // 16-bit prefix buckets
#define RANK_CAP 32768

// ===== Bit-exact replica of XLA's f32 tanh =====
__device__ __forceinline__ float xla_tanhf(float x) {
    float xc = fminf(fmaxf(x, -9.0f), 9.0f);
    float x2 = __fmul_rn(xc, xc);
    float p = -2.76076847742355e-16f;
    p = __fadd_rn(__fmul_rn(p, x2),  2.00018790482477e-13f);
    p = __fadd_rn(__fmul_rn(p, x2), -8.60467152213735e-11f);
    p = __fadd_rn(__fmul_rn(p, x2),  5.12229709037114e-08f);
    p = __fadd_rn(__fmul_rn(p, x2),  1.48572235717979e-05f);
    p = __fadd_rn(__fmul_rn(p, x2),  6.37261928875436e-04f);
    p = __fadd_rn(__fmul_rn(p, x2),  4.89352455891786e-03f);
    p = __fmul_rn(xc, p);
    float q = 1.19825839466702e-06f;
    q = __fadd_rn(__fmul_rn(q, x2),  1.18534705686654e-04f);
    q = __fadd_rn(__fmul_rn(q, x2),  2.26843463243900e-03f);
    q = __fadd_rn(__fmul_rn(q, x2),  4.89352518554385e-03f);
    float r = p / q;                     // IEEE f32 divide
    return (fabsf(x) < 0.0004f) ? x : r;
}

__device__ __forceinline__ u32 key_desc(float f) {
    u32 u = __float_as_uint(f);
    u = (u & 0x80000000u) ? ~u : (u | 0x80000000u);
    return ~u;
}

// zero hist + flags (contiguous)
__global__ void k_zero(u32* __restrict__ p, int n) {
    int i = blockIdx.x * blockDim.x + threadIdx.x;
    if (i < n) p[i] = 0;
}

// tanh table + cluster init + bucket histogram + int64/int32 layout detect
__global__ void k_prep(const float* __restrict__ score, float* __restrict__ s,
                       int* __restrict__ cluster, u32* __restrict__ hist,
                       const int* __restrict__ ei, const int* __restrict__ ntype,
                       u32* __restrict__ flags, int N) {
    int i = blockIdx.x * blockDim.x + threadIdx.x;
    if (i < 2048) { if (ei[2 * i + 1] != 0) atomicOr(&flags[0], 1u); }
    else if (i < 4096) { int j = i - 2048; if (ntype[2 * j + 1] != 0) atomicOr(&flags[1], 1u); }
    if (i < N) {
        float t = xla_tanhf(score[i]);
        s[i] = t;
        cluster[i] = -1;
        atomicAdd(&hist[key_desc(t) >> 16], 1u);
    }
}

// 256 blocks: block b reduces hist[b*256 .. +255] -> part[b]
__global__ void k_scanA(const u32* __restrict__ hist, u32* __restrict__ part) {
    __shared__ u32 sh[256];
    int b = blockIdx.x, t = threadIdx.x;
    sh[t] = hist[b * 256 + t];
    __syncthreads();
    for (int off = 128; off > 0; off >>= 1) {
        if (t < off) sh[t] += sh[t + off];
        __syncthreads();
    }
    if (t == 0) part[b] = sh[0];
}

// 256 blocks: base = sum(part[0..b)), chunk-scan, write scan[] AND cursor[]
__global__ void k_scanB(const u32* __restrict__ hist, const u32* __restrict__ part,
                        u32* __restrict__ scan, u32* __restrict__ cursor) {
    __shared__ u32 sh[256];
    __shared__ u32 base_sh;
    int b = blockIdx.x, t = threadIdx.x;
    u32 acc = (t < b) ? part[t] : 0u;
    sh[t] = acc;
    __syncthreads();
    for (int off = 128; off > 0; off >>= 1) {
        if (t < off) sh[t] += sh[t + off];
        __syncthreads();
    }
    if (t == 0) base_sh = sh[0];
    __syncthreads();
    u32 base = base_sh;
    u32 v = hist[b * 256 + t];
    sh[t] = v;
    __syncthreads();
    for (int off = 1; off < 256; off <<= 1) {
        u32 x = sh[t];
        u32 y = (t >= off) ? sh[t - off] : 0u;
        __syncthreads();
        sh[t] = x + y;
        __syncthreads();
    }
    u32 ex = base + sh[t] - v;           // exclusive prefix
    scan[b * 256 + t] = ex;
    cursor[b * 256 + t] = ex;
    if (b == 255 && t == 255) scan[NBKT] = ex + v;   // total = N
}

// scatter packed (key<<32|idx); cursor already holds the bucket base
__global__ void k_scat(const float* __restrict__ s, u32* __restrict__ cursor,
                       u64* __restrict__ pack, int N) {
    int i = blockIdx.x * blockDim.x + threadIdx.x;
    if (i < N) {
        u32 kk = key_desc(s[i]);
        u32 pos = atomicAdd(&cursor[kk >> 16], 1u);
        if (pos < (u32)N) pack[pos] = ((u64)kk << 32) | (u32)i;
    }
}

// exact in-bucket rank (single u64 compare) + fused perm outputs
__global__ void k_rankperm(const u32* __restrict__ scan, const u64* __restrict__ pack,
                           u32* __restrict__ pay, const float* __restrict__ s,
                           const int* __restrict__ ntype, const u32* __restrict__ ntFlag,
                           int* __restrict__ cluster,
                           float* __restrict__ o_nt, float* __restrict__ o_perm,
                           float* __restrict__ o_vals, int k, int N) {
    int i = blockIdx.x * blockDim.x + threadIdx.x;
    if (i < N) {
        u64 pk = pack[i];
        u32 b = (u32)(pk >> 48);
        u32 lo = scan[b], hi = scan[b + 1];
        if (hi > (u32)N) hi = (u32)N;
        if (hi > lo + RANK_CAP) hi = lo + RANK_CAP;
        u32 r = lo;
        for (u32 q = lo; q < hi; ++q) r += (pack[q] < pk);
        if (r < (u32)k) {
            u32 ip = (u32)pk;
            if (ip >= (u32)N) ip = 0;      // defensive
            pay[r] = ip;
            cluster[ip] = (int)r;
            o_perm[r] = (float)ip;
            o_vals[r] = s[ip];
            int nt = (*ntFlag == 0u) ? ntype[2 * (size_t)ip] : ntype[ip];
            o_nt[r] = (float)nt;
        }
    }
}

// x-gather (R10-proven: regular loads, NT store)
__global__ void k_gx(const u32* __restrict__ pay, const float* __restrict__ s,
                     const f32x4* __restrict__ x4, f32x4* __restrict__ out4,
                     int k, int Dv, int N) {
    int idx = blockIdx.x * blockDim.x + threadIdx.x;
    if (idx < k * Dv) {
        int r = idx / Dv, c = idx - r * Dv;
        u32 p = pay[r];
        if (p >= (u32)N) p = 0;
        float v = s[p];
        f32x4 a = x4[(size_t)p * Dv + c];
        a = a * v;
        __builtin_nontemporal_store(a, out4 + idx);
    }
}

// QUAD-fused edges+attr (R10-proven: regular loads, NT stores)
__global__ void k_ea(const int* __restrict__ ei, const u32* __restrict__ eiFlag,
                     const float* __restrict__ elen, const int* __restrict__ cluster,
                     const f32x4* __restrict__ attr4,
                     float* __restrict__ o_ei, float* __restrict__ o_len,
                     float* __restrict__ o_mask, f32x4* __restrict__ o_attr4,
                     int E, int N) {
    const int total = E * 4;
    const int stride = gridDim.x * blockDim.x;
    const bool w64 = (*eiFlag == 0u);
    for (int idx = blockIdx.x * blockDim.x + threadIdx.x; idx < total; idx += stride) {
        int e = idx >> 2, c = idx & 3;
        int mfl = 0;
        if (c == 0) {
            int a, b;
            if (w64) { a = ei[2 * (size_t)e]; b = ei[2 * ((size_t)E + (size_t)e)]; }
            else { a = ei[e]; b = ei[E + e]; }
            bool ok = ((u32)a < (u32)N) && ((u32)b < (u32)N);
            int r = ok ? cluster[a] : -1;
            int cc = ok ? cluster[b] : -1;
            bool m = (r >= 0) && (cc >= 0);
            mfl = m ? 1 : 0;
            __builtin_nontemporal_store(m ? (float)r  : 0.0f, o_ei + e);
            __builtin_nontemporal_store(m ? (float)cc : 0.0f, o_ei + (size_t)E + e);
            __builtin_nontemporal_store(m ? elen[e] : 0.0f, o_len + e);
            __builtin_nontemporal_store(m ? 1.0f : 0.0f, o_mask + e);
        }
        int lane = threadIdx.x & 63;
        mfl = __shfl(mfl, lane & ~3);
        f32x4 v = {0.f, 0.f, 0.f, 0.f};
        if (mfl) v = attr4[idx];
        __builtin_nontemporal_store(v, o_attr4 + idx);
    }
}

extern "C" void kernel_launch(void* const* d_in, const int* in_sizes, int n_in,
                              void* d_out, int out_size, void* d_ws, size_t ws_size,
                              hipStream_t stream) {
    const float* x     = (const float*)d_in[0];
    const float* score = (const float*)d_in[1];
    const int*   ei    = (const int*)d_in[2];
    const float* eattr = (const float*)d_in[3];
    const int*   ntype = (const int*)d_in[4];
    const float* elen  = (const float*)d_in[5];

    const int N  = in_sizes[1];
    const int D  = in_sizes[0] / N;
    const int E  = in_sizes[5];
    const int DE = in_sizes[3] / E;
    const int k  = (N + 1) / 2;     // ceil(0.5 * N)

    // d_out is FLOAT32. RETURN-ORDER layout:
    // x_p | edge_index | edge_attr_p | node_type | perm | vals | edge_lengths | edge_mask
    float* out = (float*)d_out;
    const size_t o_xp    = 0;
    const size_t o_ei    = o_xp    + (size_t)k * D;
    const size_t o_eattr = o_ei    + 2 * (size_t)E;
    const size_t o_nt    = o_eattr + (size_t)E * DE;
    const size_t o_perm  = o_nt    + (size_t)k;
    const size_t o_vals  = o_perm  + (size_t)k;
    const size_t o_elen  = o_vals  + (size_t)k;
    const size_t o_emask = o_elen  + (size_t)E;

    char* ws = (char*)d_ws;
    u64* pack    = (u64*)ws;     ws += 8 * (size_t)N;       // 8B-aligned first
    float* s     = (float*)ws;   ws += 4 * (size_t)N;
    u32* hist    = (u32*)ws;     ws += 4 * (size_t)NBKT;
    u32* flags   = (u32*)ws;     ws += 4 * 2;               // contiguous with hist
    u32* scan    = (u32*)ws;     ws += 4 * ((size_t)NBKT + 2);
    u32* cursor  = (u32*)ws;     ws += 4 * (size_t)NBKT;    // init'd by k_scanB
    u32* part    = (u32*)ws;     ws += 4 * 256;
    u32* pay     = (u32*)ws;     ws += 4 * (size_t)N;
    int* cluster = (int*)ws;     ws += 4 * (size_t)N;

    const int nbN = (N + 255) / 256;
    k_zero<<<(NBKT + 2 + 255) / 256, 256, 0, stream>>>(hist, NBKT + 2);
    k_prep<<<nbN, 256, 0, stream>>>(score, s, cluster, hist, ei, ntype, flags, N);
    k_scanA<<<256, 256, 0, stream>>>(hist, part);
    k_scanB<<<256, 256, 0, stream>>>(hist, part, scan, cursor);
    k_scat<<<nbN, 256, 0, stream>>>(s, cursor, pack, N);
    k_rankperm<<<nbN, 256, 0, stream>>>(scan, pack, pay, s, ntype, &flags[1], cluster,
                                        out + o_nt, out + o_perm, out + o_vals, k, N);
    const int Dv = D / 4;
    const int gx = k * Dv;
    k_gx<<<(gx + 255) / 256, 256, 0, stream>>>(pay, s, (const f32x4*)x,
                                               (f32x4*)(out + o_xp), k, Dv, N);
    k_ea<<<2048, 256, 0, stream>>>(ei, &flags[0], elen, cluster,
                                   (const f32x4*)eattr,
                                   out + o_ei, out + o_elen, out + o_emask,
                                   (f32x4*)(out + o_eattr), E, N);
}